// Round 1
// baseline (257.854 us; speedup 1.0000x reference)
//
#include <hip/hip_runtime.h>
#include <hip/hip_bf16.h>
#include <stdint.h>

#define NROW 8192
#define DIM  512
#define BM   128
#define BN   128
#define BK   64

typedef float  f32x4  __attribute__((ext_vector_type(4)));
typedef __bf16 bf16x8 __attribute__((ext_vector_type(8)));

__device__ __forceinline__ unsigned short f32_to_bf16(float f) {
    unsigned int x = __float_as_uint(f);
    x += 0x7fffu + ((x >> 16) & 1u);   // round-to-nearest-even
    return (unsigned short)(x >> 16);
}

// ---------------------------------------------------------------------------
// prep: z (fp32) -> zbf (bf16, RNE), sq[i] = sum_k z[i][k]^2 (fp32),
//       hist[c] = count of rows with label c.
// One wave per row: 64 lanes x 8 floats = 512.
// ---------------------------------------------------------------------------
__global__ __launch_bounds__(256) void prep_kernel(
    const float* __restrict__ z, const int* __restrict__ labels,
    unsigned short* __restrict__ zbf, float* __restrict__ sq,
    int* __restrict__ hist)
{
    const int lane = threadIdx.x & 63;
    const int wave = threadIdx.x >> 6;
    const int row  = blockIdx.x * 4 + wave;

    const float4* zr = (const float4*)(z + (size_t)row * DIM);
    float4 v0 = zr[lane * 2 + 0];
    float4 v1 = zr[lane * 2 + 1];
    float s = v0.x*v0.x + v0.y*v0.y + v0.z*v0.z + v0.w*v0.w
            + v1.x*v1.x + v1.y*v1.y + v1.z*v1.z + v1.w*v1.w;

    union { unsigned short u[8]; int4 v; } pk;
    pk.u[0] = f32_to_bf16(v0.x); pk.u[1] = f32_to_bf16(v0.y);
    pk.u[2] = f32_to_bf16(v0.z); pk.u[3] = f32_to_bf16(v0.w);
    pk.u[4] = f32_to_bf16(v1.x); pk.u[5] = f32_to_bf16(v1.y);
    pk.u[6] = f32_to_bf16(v1.z); pk.u[7] = f32_to_bf16(v1.w);
    ((int4*)(zbf + (size_t)row * DIM))[lane] = pk.v;

    #pragma unroll
    for (int sft = 1; sft < 64; sft <<= 1) s += __shfl_xor(s, sft);
    if (lane == 0) {
        sq[row] = s;
        atomicAdd(&hist[labels[row]], 1);
    }
}

// ---------------------------------------------------------------------------
// main: 128x128 tile of the Gram matrix via 16x16x32 bf16 MFMA, fused
// distance + label-masked row-sum epilogue. 4 waves, each owns 64x64.
// LDS tiles are [row][k] with XOR swizzle byte^=((row&7)<<4) applied by
// pre-swizzling the *global* source (global_load_lds writes linearly) and
// applying the same XOR on ds_read (rule #21: both-sides-or-neither).
// ---------------------------------------------------------------------------
__global__ __launch_bounds__(256) void tile_kernel(
    const unsigned short* __restrict__ zbf,
    const float* __restrict__ sq, const int* __restrict__ labels,
    float* __restrict__ pos_sum, float* __restrict__ neg_sum)
{
    __shared__ unsigned short As[BM * BK];  // 16 KiB
    __shared__ unsigned short Bs[BN * BK];  // 16 KiB

    const int tid  = threadIdx.x;
    const int lane = tid & 63;
    const int wave = tid >> 6;
    const int wm = wave >> 1;   // 0..1
    const int wn = wave & 1;    // 0..1

    const int bid  = blockIdx.x;
    const int tm   = bid >> 6;
    const int tn   = bid & 63;
    const int row0 = tm * BM;
    const int col0 = tn * BN;

    f32x4 acc[4][4];
    #pragma unroll
    for (int m = 0; m < 4; ++m)
        #pragma unroll
        for (int n = 0; n < 4; ++n)
            acc[m][n] = (f32x4){0.f, 0.f, 0.f, 0.f};

    // staging geometry: thread t covers LDS linear bytes [r*4096 + t*16).
    // LDS row = r*32 + t/8 (128B per row), inner byte = (t&7)*16.
    // data that belongs there (post-XOR-swizzle) is global k-byte inner^((row&7)<<4).
    const int srow   = tid >> 3;                       // 0..31
    const int sinner = (tid & 7) << 4;                 // 0..112
    const int kbsw   = sinner ^ ((srow & 7) << 4);     // (r*32)&7 == 0, so r-invariant
    const size_t gA = (size_t)row0 * DIM + (size_t)srow * DIM + (kbsw >> 1);
    const size_t gB = (size_t)col0 * DIM + (size_t)srow * DIM + (kbsw >> 1);

    for (int k0 = 0; k0 < DIM; k0 += BK) {
        #pragma unroll
        for (int r = 0; r < 4; ++r) {
            const unsigned short* srcA = zbf + gA + (size_t)r * 32 * DIM + k0;
            const unsigned short* srcB = zbf + gB + (size_t)r * 32 * DIM + k0;
            __builtin_amdgcn_global_load_lds(
                (const __attribute__((address_space(1))) void*)srcA,
                (__attribute__((address_space(3))) void*)((char*)As + r * 4096 + tid * 16),
                16, 0, 0);
            __builtin_amdgcn_global_load_lds(
                (const __attribute__((address_space(1))) void*)srcB,
                (__attribute__((address_space(3))) void*)((char*)Bs + r * 4096 + tid * 16),
                16, 0, 0);
        }
        __syncthreads();

        #pragma unroll
        for (int kk = 0; kk < BK; kk += 32) {
            const int kbyte = (kk + ((lane >> 4) << 3)) * 2;  // 16B-aligned
            bf16x8 af[4], bg[4];
            #pragma unroll
            for (int m = 0; m < 4; ++m) {
                int rowl = wm * 64 + m * 16 + (lane & 15);
                int off  = rowl * 128 + (kbyte ^ ((rowl & 7) << 4));
                af[m] = *(const bf16x8*)((const char*)As + off);
            }
            #pragma unroll
            for (int n = 0; n < 4; ++n) {
                int coll = wn * 64 + n * 16 + (lane & 15);
                int off  = coll * 128 + (kbyte ^ ((coll & 7) << 4));
                bg[n] = *(const bf16x8*)((const char*)Bs + off);
            }
            #pragma unroll
            for (int m = 0; m < 4; ++m)
                #pragma unroll
                for (int n = 0; n < 4; ++n)
                    acc[m][n] = __builtin_amdgcn_mfma_f32_16x16x32_bf16(
                        af[m], bg[n], acc[m][n], 0, 0, 0);
        }
        __syncthreads();
    }

    // ---- fused epilogue: dist -> label-masked row sums -> atomics ----
    // C/D map (m89-verified): col = lane&15, row = (lane>>4)*4 + r
    const int colbase = col0 + wn * 64;
    float col_sq[4]; int col_lb[4];
    #pragma unroll
    for (int n = 0; n < 4; ++n) {
        int cg = colbase + n * 16 + (lane & 15);
        col_sq[n] = sq[cg];
        col_lb[n] = labels[cg];
    }
    const int hi = lane >> 4;
    #pragma unroll
    for (int m = 0; m < 4; ++m) {
        #pragma unroll
        for (int r = 0; r < 4; ++r) {
            const int rg = row0 + wm * 64 + m * 16 + hi * 4 + r;
            const float rs = sq[rg];
            const int   rl = labels[rg];
            float pos = 0.f, neg = 0.f;
            #pragma unroll
            for (int n = 0; n < 4; ++n) {
                float d2   = rs + col_sq[n] - 2.0f * acc[m][n][r];
                float dist = d2 > 0.f ? sqrtf(d2) : 0.f;
                int cg = colbase + n * 16 + (lane & 15);
                if (cg == rg) dist = 0.f;          // exact-zero diagonal
                if (rl == col_lb[n]) pos += dist; else neg += dist;
            }
            #pragma unroll
            for (int s = 1; s < 16; s <<= 1) {
                pos += __shfl_xor(pos, s);
                neg += __shfl_xor(neg, s);
            }
            if ((lane & 15) == 0) {
                atomicAdd(&pos_sum[rg], pos);
                atomicAdd(&neg_sum[rg], neg);
            }
        }
    }
}

// ---------------------------------------------------------------------------
// row loss + reduce
// ---------------------------------------------------------------------------
__global__ __launch_bounds__(256) void rowloss_kernel(
    const float* __restrict__ pos_sum, const float* __restrict__ neg_sum,
    const int* __restrict__ labels, const int* __restrict__ hist,
    float* __restrict__ totals)
{
    const int i = blockIdx.x * 256 + threadIdx.x;   // grid = 32 -> covers 8192
    const float pc = (float)hist[labels[i]];        // includes self
    const float nc = (float)NROW - pc;
    const float pm = pos_sum[i] / fmaxf(pc, 1.f);
    const float nm = neg_sum[i] / fmaxf(nc, 1.f);
    const bool valid = (pc > 1.f) && (nc > 0.f);
    float t = valid ? fmaxf(pm - nm + 1.0f, 0.f) : 0.f;
    float c = valid ? 1.f : 0.f;
    #pragma unroll
    for (int s = 1; s < 64; s <<= 1) {
        t += __shfl_xor(t, s);
        c += __shfl_xor(c, s);
    }
    if ((threadIdx.x & 63) == 0) {
        atomicAdd(&totals[0], t);
        atomicAdd(&totals[1], c);
    }
}

__global__ void finalize_kernel(const float* __restrict__ totals,
                                float* __restrict__ out)
{
    out[0] = totals[0] / fmaxf(totals[1], 1.f);
}

// ---------------------------------------------------------------------------
extern "C" void kernel_launch(void* const* d_in, const int* in_sizes, int n_in,
                              void* d_out, int out_size, void* d_ws, size_t ws_size,
                              hipStream_t stream) {
    (void)in_sizes; (void)n_in; (void)out_size; (void)ws_size;
    const float* z      = (const float*)d_in[0];
    const int*   labels = (const int*)d_in[1];
    float*       out    = (float*)d_out;

    char* ws = (char*)d_ws;
    float* pos_sum = (float*)(ws);                       // 32768 B
    float* neg_sum = (float*)(ws + 32768);               // 32768 B
    int*   hist    = (int*)  (ws + 65536);               // 256 B
    float* totals  = (float*)(ws + 65792);               // 8 B
    unsigned short* zbf = (unsigned short*)(ws + 66048); // 8 MiB
    float* sq      = (float*)(ws + 66048 + (size_t)NROW * DIM * 2);

    // zero accumulators (ws is poisoned 0xAA and never re-poisoned)
    hipMemsetAsync(d_ws, 0, 65800, stream);

    prep_kernel   <<<NROW / 4, 256, 0, stream>>>(z, labels, zbf, sq, hist);
    tile_kernel   <<<(NROW / BM) * (NROW / BN), 256, 0, stream>>>(zbf, sq, labels, pos_sum, neg_sum);
    rowloss_kernel<<<NROW / 256, 256, 0, stream>>>(pos_sum, neg_sum, labels, hist, totals);
    finalize_kernel<<<1, 1, 0, stream>>>(totals, out);
}

// Round 2
// 206.817 us; speedup vs baseline: 1.2468x; 1.2468x over previous
//
#include <hip/hip_runtime.h>
#include <hip/hip_bf16.h>
#include <stdint.h>

#define NROW 8192
#define DIM  512
#define BM   256
#define BN   256
#define BK   64
#define NT   (NROW / BM)          // 32 tile rows/cols
#define NBLK (NT * (NT + 1) / 2)  // 528 upper-triangular tiles

typedef float  f32x4  __attribute__((ext_vector_type(4)));
typedef __bf16 bf16x8 __attribute__((ext_vector_type(8)));

__device__ __forceinline__ unsigned short f32_to_bf16(float f) {
    unsigned int x = __float_as_uint(f);
    x += 0x7fffu + ((x >> 16) & 1u);   // round-to-nearest-even
    return (unsigned short)(x >> 16);
}

// ---------------------------------------------------------------------------
// prep: z (fp32) -> zbf (bf16, RNE), sq[i] = sum_k z[i][k]^2 (fp32),
//       hist[c] = count of rows with label c.  One wave per row.
// ---------------------------------------------------------------------------
__global__ __launch_bounds__(256) void prep_kernel(
    const float* __restrict__ z, const int* __restrict__ labels,
    unsigned short* __restrict__ zbf, float* __restrict__ sq,
    int* __restrict__ hist)
{
    const int lane = threadIdx.x & 63;
    const int wave = threadIdx.x >> 6;
    const int row  = blockIdx.x * 4 + wave;

    const float4* zr = (const float4*)(z + (size_t)row * DIM);
    float4 v0 = zr[lane * 2 + 0];
    float4 v1 = zr[lane * 2 + 1];
    float s = v0.x*v0.x + v0.y*v0.y + v0.z*v0.z + v0.w*v0.w
            + v1.x*v1.x + v1.y*v1.y + v1.z*v1.z + v1.w*v1.w;

    union { unsigned short u[8]; int4 v; } pk;
    pk.u[0] = f32_to_bf16(v0.x); pk.u[1] = f32_to_bf16(v0.y);
    pk.u[2] = f32_to_bf16(v0.z); pk.u[3] = f32_to_bf16(v0.w);
    pk.u[4] = f32_to_bf16(v1.x); pk.u[5] = f32_to_bf16(v1.y);
    pk.u[6] = f32_to_bf16(v1.z); pk.u[7] = f32_to_bf16(v1.w);
    ((int4*)(zbf + (size_t)row * DIM))[lane] = pk.v;

    #pragma unroll
    for (int sft = 1; sft < 64; sft <<= 1) s += __shfl_xor(s, sft);
    if (lane == 0) {
        sq[row] = s;
        atomicAdd(&hist[labels[row]], 1);
    }
}

// ---------------------------------------------------------------------------
// tile: one 256x256 Gram tile (upper triangle only) via 16x16x32 bf16 MFMA,
// double-buffered LDS (T3 minimum 2-phase), fused dist + label-masked
// row-sum AND col-sum epilogue (symmetry: dist/same are symmetric).
// 8 waves (2x4): wave tile = 128 rows x 64 cols, acc[8][4].
// ---------------------------------------------------------------------------
__global__ __launch_bounds__(512) void tile_kernel(
    const unsigned short* __restrict__ zbf,
    const float* __restrict__ sq, const int* __restrict__ labels,
    float* __restrict__ pos_sum, float* __restrict__ neg_sum)
{
    __shared__ unsigned short As[2][BM * BK];  // 2 x 32 KiB
    __shared__ unsigned short Bs[2][BN * BK];  // 2 x 32 KiB

    const int tid  = threadIdx.x;
    const int lane = tid & 63;
    const int wave = tid >> 6;
    const int wm = wave >> 2;   // 0..1 -> 128-row half
    const int wn = wave & 3;    // 0..3 -> 64-col quarter

    // XCD-chunked bijective remap (528 = 8*66), then triangular decode
    const int bid  = (int)blockIdx.x;
    int bidx = (bid & 7) * (NBLK / 8) + (bid >> 3);
    int tm = 0, rem = bidx;
    while (rem >= NT - tm) { rem -= NT - tm; ++tm; }
    const int tn = tm + rem;
    const int row0 = tm * BM;
    const int col0 = tn * BN;
    const bool offdiag = (tm != tn);

    f32x4 acc[8][4];
    #pragma unroll
    for (int m = 0; m < 8; ++m)
        #pragma unroll
        for (int n = 0; n < 4; ++n)
            acc[m][n] = (f32x4){0.f, 0.f, 0.f, 0.f};

    // staging: 512 threads x 16B x 4 calls = 32 KiB per matrix per K-step.
    // LDS row = r*64 + tid/8 (128 B rows); global k pre-swizzled so that the
    // XOR-swizzled ds_read sees the right data (rule #21).
    const int srow   = tid >> 3;                    // 0..63
    const int sinner = (tid & 7) << 4;
    const int kbsw   = sinner ^ ((srow & 7) << 4);  // r*64 is 8-aligned -> r-invariant
    const unsigned short* baseA = zbf + (size_t)(row0 + srow) * DIM + (kbsw >> 1);
    const unsigned short* baseB = zbf + (size_t)(col0 + srow) * DIM + (kbsw >> 1);

#define STAGE(buf, k0)                                                         \
    do {                                                                       \
        _Pragma("unroll")                                                      \
        for (int r = 0; r < 4; ++r) {                                          \
            __builtin_amdgcn_global_load_lds(                                  \
                (const __attribute__((address_space(1))) void*)(baseA + (size_t)r * 64 * DIM + (k0)), \
                (__attribute__((address_space(3))) void*)((char*)As[buf] + r * 8192 + tid * 16), 16, 0, 0); \
            __builtin_amdgcn_global_load_lds(                                  \
                (const __attribute__((address_space(1))) void*)(baseB + (size_t)r * 64 * DIM + (k0)), \
                (__attribute__((address_space(3))) void*)((char*)Bs[buf] + r * 8192 + tid * 16), 16, 0, 0); \
        }                                                                      \
    } while (0)

#define COMPUTE(buf)                                                           \
    do {                                                                       \
        _Pragma("unroll")                                                      \
        for (int kk = 0; kk < BK; kk += 32) {                                  \
            const int kbyte = (kk + ((lane >> 4) << 3)) * 2;                   \
            bf16x8 bg[4];                                                      \
            _Pragma("unroll")                                                  \
            for (int n = 0; n < 4; ++n) {                                      \
                int coll = wn * 64 + n * 16 + (lane & 15);                     \
                bg[n] = *(const bf16x8*)((const char*)Bs[buf] + coll * 128 + (kbyte ^ ((coll & 7) << 4))); \
            }                                                                  \
            _Pragma("unroll")                                                  \
            for (int m = 0; m < 8; ++m) {                                      \
                int rowl = wm * 128 + m * 16 + (lane & 15);                    \
                bf16x8 af = *(const bf16x8*)((const char*)As[buf] + rowl * 128 + (kbyte ^ ((rowl & 7) << 4))); \
                _Pragma("unroll")                                              \
                for (int n = 0; n < 4; ++n)                                    \
                    acc[m][n] = __builtin_amdgcn_mfma_f32_16x16x32_bf16(af, bg[n], acc[m][n], 0, 0, 0); \
            }                                                                  \
        }                                                                      \
    } while (0)

    STAGE(0, 0);
    __syncthreads();                 // compiler emits vmcnt(0) drain here
    int cur = 0;
    #pragma unroll 1
    for (int t = 0; t < (DIM / BK) - 1; ++t) {
        STAGE(cur ^ 1, (t + 1) * BK);   // issue next-tile loads FIRST
        COMPUTE(cur);                    // ds_read + MFMA on current
        __syncthreads();                 // one vmcnt(0)+barrier per K-step
        cur ^= 1;
    }
    COMPUTE(cur);

    // ---- fused epilogue ----
    // C/D map: col = lane&15, row = (lane>>4)*4 + r  (m89-verified)
    const int colbase = col0 + wn * 64;
    const int hi = lane >> 4;
    float csq[4]; int clb[4];
    #pragma unroll
    for (int n = 0; n < 4; ++n) {
        int cg = colbase + n * 16 + (lane & 15);
        csq[n] = sq[cg];
        clb[n] = labels[cg];
    }
    float cpos[4] = {0.f, 0.f, 0.f, 0.f};
    float cneg[4] = {0.f, 0.f, 0.f, 0.f};

    #pragma unroll
    for (int m = 0; m < 8; ++m) {
        #pragma unroll
        for (int r = 0; r < 4; ++r) {
            const int rg = row0 + wm * 128 + m * 16 + hi * 4 + r;
            const float rs = sq[rg];
            const int   rl = labels[rg];
            float pos = 0.f, neg = 0.f;
            #pragma unroll
            for (int n = 0; n < 4; ++n) {
                float d2   = rs + csq[n] - 2.0f * acc[m][n][r];
                float dist = d2 > 0.f ? sqrtf(d2) : 0.f;
                int cg = colbase + n * 16 + (lane & 15);
                if (cg == rg) dist = 0.f;          // exact-zero diagonal
                bool same = (rl == clb[n]);
                float dp = same ? dist : 0.f;
                float dn = same ? 0.f : dist;
                pos += dp;  neg += dn;
                cpos[n] += dp;  cneg[n] += dn;     // column sums (symmetry)
            }
            #pragma unroll
            for (int s = 1; s < 16; s <<= 1) {
                pos += __shfl_xor(pos, s);
                neg += __shfl_xor(neg, s);
            }
            if ((lane & 15) == 0) {
                atomicAdd(&pos_sum[rg], pos);
                atomicAdd(&neg_sum[rg], neg);
            }
        }
    }

    if (offdiag) {
        #pragma unroll
        for (int n = 0; n < 4; ++n) {
            cpos[n] += __shfl_xor(cpos[n], 16);
            cpos[n] += __shfl_xor(cpos[n], 32);
            cneg[n] += __shfl_xor(cneg[n], 16);
            cneg[n] += __shfl_xor(cneg[n], 32);
            if (lane < 16) {
                int cg = colbase + n * 16 + lane;
                atomicAdd(&pos_sum[cg], cpos[n]);
                atomicAdd(&neg_sum[cg], cneg[n]);
            }
        }
    }
#undef STAGE
#undef COMPUTE
}

// ---------------------------------------------------------------------------
__global__ __launch_bounds__(256) void rowloss_kernel(
    const float* __restrict__ pos_sum, const float* __restrict__ neg_sum,
    const int* __restrict__ labels, const int* __restrict__ hist,
    float* __restrict__ totals)
{
    const int i = blockIdx.x * 256 + threadIdx.x;
    const float pc = (float)hist[labels[i]];        // includes self
    const float nc = (float)NROW - pc;
    const float pm = pos_sum[i] / fmaxf(pc, 1.f);
    const float nm = neg_sum[i] / fmaxf(nc, 1.f);
    const bool valid = (pc > 1.f) && (nc > 0.f);
    float t = valid ? fmaxf(pm - nm + 1.0f, 0.f) : 0.f;
    float c = valid ? 1.f : 0.f;
    #pragma unroll
    for (int s = 1; s < 64; s <<= 1) {
        t += __shfl_xor(t, s);
        c += __shfl_xor(c, s);
    }
    if ((threadIdx.x & 63) == 0) {
        atomicAdd(&totals[0], t);
        atomicAdd(&totals[1], c);
    }
}

__global__ void finalize_kernel(const float* __restrict__ totals,
                                float* __restrict__ out)
{
    out[0] = totals[0] / fmaxf(totals[1], 1.f);
}

// ---------------------------------------------------------------------------
extern "C" void kernel_launch(void* const* d_in, const int* in_sizes, int n_in,
                              void* d_out, int out_size, void* d_ws, size_t ws_size,
                              hipStream_t stream) {
    (void)in_sizes; (void)n_in; (void)out_size; (void)ws_size;
    const float* z      = (const float*)d_in[0];
    const int*   labels = (const int*)d_in[1];
    float*       out    = (float*)d_out;

    char* ws = (char*)d_ws;
    float* pos_sum = (float*)(ws);                       // 32768 B
    float* neg_sum = (float*)(ws + 32768);               // 32768 B
    int*   hist    = (int*)  (ws + 65536);               // 256 B
    float* totals  = (float*)(ws + 65792);               // 8 B
    unsigned short* zbf = (unsigned short*)(ws + 66048); // 8 MiB
    float* sq      = (float*)(ws + 66048 + (size_t)NROW * DIM * 2);

    // zero accumulators (ws is poisoned 0xAA and never re-poisoned)
    hipMemsetAsync(d_ws, 0, 65800, stream);

    prep_kernel    <<<NROW / 4, 256, 0, stream>>>(z, labels, zbf, sq, hist);
    tile_kernel    <<<NBLK, 512, 0, stream>>>(zbf, sq, labels, pos_sum, neg_sum);
    rowloss_kernel <<<NROW / 256, 256, 0, stream>>>(pos_sum, neg_sum, labels, hist, totals);
    finalize_kernel<<<1, 1, 0, stream>>>(totals, out);
}

// Round 3
// 176.761 us; speedup vs baseline: 1.4588x; 1.1700x over previous
//
#include <hip/hip_runtime.h>
#include <hip/hip_bf16.h>
#include <stdint.h>

#define NROW 8192
#define DIM  512
#define BM   256
#define BN   256
#define BK   64
#define NT   (NROW / BM)          // 32 tile rows/cols
#define NBLK (NT * (NT + 1) / 2)  // 528 upper-triangular tiles

typedef float  f32x4  __attribute__((ext_vector_type(4)));
typedef __bf16 bf16x8 __attribute__((ext_vector_type(8)));

__device__ __forceinline__ unsigned short f32_to_bf16(float f) {
    unsigned int x = __float_as_uint(f);
    x += 0x7fffu + ((x >> 16) & 1u);   // round-to-nearest-even
    return (unsigned short)(x >> 16);
}

// ---------------------------------------------------------------------------
// prep: z (fp32) -> zbf (bf16, RNE), sq[i] = sum_k z[i][k]^2 (fp32),
//       hist[c] = count of rows with label c.  One wave per row.
// ---------------------------------------------------------------------------
__global__ __launch_bounds__(256) void prep_kernel(
    const float* __restrict__ z, const int* __restrict__ labels,
    unsigned short* __restrict__ zbf, float* __restrict__ sq,
    int* __restrict__ hist)
{
    const int lane = threadIdx.x & 63;
    const int wave = threadIdx.x >> 6;
    const int row  = blockIdx.x * 4 + wave;

    const float4* zr = (const float4*)(z + (size_t)row * DIM);
    float4 v0 = zr[lane * 2 + 0];
    float4 v1 = zr[lane * 2 + 1];
    float s = v0.x*v0.x + v0.y*v0.y + v0.z*v0.z + v0.w*v0.w
            + v1.x*v1.x + v1.y*v1.y + v1.z*v1.z + v1.w*v1.w;

    union { unsigned short u[8]; int4 v; } pk;
    pk.u[0] = f32_to_bf16(v0.x); pk.u[1] = f32_to_bf16(v0.y);
    pk.u[2] = f32_to_bf16(v0.z); pk.u[3] = f32_to_bf16(v0.w);
    pk.u[4] = f32_to_bf16(v1.x); pk.u[5] = f32_to_bf16(v1.y);
    pk.u[6] = f32_to_bf16(v1.z); pk.u[7] = f32_to_bf16(v1.w);
    ((int4*)(zbf + (size_t)row * DIM))[lane] = pk.v;

    #pragma unroll
    for (int sft = 1; sft < 64; sft <<= 1) s += __shfl_xor(s, sft);
    if (lane == 0) {
        sq[row] = s;
        atomicAdd(&hist[labels[row]], 1);
    }
}

// ---------------------------------------------------------------------------
// tile: one 256x256 Gram tile (upper triangle only) via 16x16x32 bf16 MFMA,
// double-buffered LDS, fused dist + label-masked row AND col sums (symmetry).
// NO global atomics: block (tm,tn) is the unique writer of
//   partial_{pos,neg}[tn][rows of tm]  (row-side)
//   partial_{pos,neg}[tm][cols of tn]  (col-side, offdiag only)
// Cross-wave combine happens in LDS (reusing the staging buffers).
// 8 waves (2x4): wave tile = 128 rows x 64 cols, acc[8][4].
// ---------------------------------------------------------------------------
__global__ __launch_bounds__(512) void tile_kernel(
    const unsigned short* __restrict__ zbf,
    const float* __restrict__ sq, const int* __restrict__ labels,
    float* __restrict__ partial_pos, float* __restrict__ partial_neg)
{
    __shared__ unsigned short As[2][BM * BK];  // 2 x 32 KiB
    __shared__ unsigned short Bs[2][BN * BK];  // 2 x 32 KiB

    const int tid  = threadIdx.x;
    const int lane = tid & 63;
    const int wave = tid >> 6;
    const int wm = wave >> 2;   // 0..1 -> 128-row half
    const int wn = wave & 3;    // 0..3 -> 64-col quarter

    // XCD-chunked bijective remap (528 = 8*66), then triangular decode
    const int bid  = (int)blockIdx.x;
    int bidx = (bid & 7) * (NBLK / 8) + (bid >> 3);
    int tm = 0, rem = bidx;
    while (rem >= NT - tm) { rem -= NT - tm; ++tm; }
    const int tn = tm + rem;
    const int row0 = tm * BM;
    const int col0 = tn * BN;
    const bool offdiag = (tm != tn);

    f32x4 acc[8][4];
    #pragma unroll
    for (int m = 0; m < 8; ++m)
        #pragma unroll
        for (int n = 0; n < 4; ++n)
            acc[m][n] = (f32x4){0.f, 0.f, 0.f, 0.f};

    // staging: 512 threads x 16B x 4 calls = 32 KiB per matrix per K-step.
    // LDS row = r*64 + tid/8 (128 B rows); global k pre-swizzled so that the
    // XOR-swizzled ds_read sees the right data (rule #21).
    const int srow   = tid >> 3;                    // 0..63
    const int sinner = (tid & 7) << 4;
    const int kbsw   = sinner ^ ((srow & 7) << 4);  // r*64 is 8-aligned -> r-invariant
    const unsigned short* baseA = zbf + (size_t)(row0 + srow) * DIM + (kbsw >> 1);
    const unsigned short* baseB = zbf + (size_t)(col0 + srow) * DIM + (kbsw >> 1);

#define STAGE(buf, k0)                                                         \
    do {                                                                       \
        _Pragma("unroll")                                                      \
        for (int r = 0; r < 4; ++r) {                                          \
            __builtin_amdgcn_global_load_lds(                                  \
                (const __attribute__((address_space(1))) void*)(baseA + (size_t)r * 64 * DIM + (k0)), \
                (__attribute__((address_space(3))) void*)((char*)As[buf] + r * 8192 + tid * 16), 16, 0, 0); \
            __builtin_amdgcn_global_load_lds(                                  \
                (const __attribute__((address_space(1))) void*)(baseB + (size_t)r * 64 * DIM + (k0)), \
                (__attribute__((address_space(3))) void*)((char*)Bs[buf] + r * 8192 + tid * 16), 16, 0, 0); \
        }                                                                      \
    } while (0)

#define COMPUTE(buf)                                                           \
    do {                                                                       \
        _Pragma("unroll")                                                      \
        for (int kk = 0; kk < BK; kk += 32) {                                  \
            const int kbyte = (kk + ((lane >> 4) << 3)) * 2;                   \
            bf16x8 bg[4];                                                      \
            _Pragma("unroll")                                                  \
            for (int n = 0; n < 4; ++n) {                                      \
                int coll = wn * 64 + n * 16 + (lane & 15);                     \
                bg[n] = *(const bf16x8*)((const char*)Bs[buf] + coll * 128 + (kbyte ^ ((coll & 7) << 4))); \
            }                                                                  \
            _Pragma("unroll")                                                  \
            for (int m = 0; m < 8; ++m) {                                      \
                int rowl = wm * 128 + m * 16 + (lane & 15);                    \
                bf16x8 af = *(const bf16x8*)((const char*)As[buf] + rowl * 128 + (kbyte ^ ((rowl & 7) << 4))); \
                _Pragma("unroll")                                              \
                for (int n = 0; n < 4; ++n)                                    \
                    acc[m][n] = __builtin_amdgcn_mfma_f32_16x16x32_bf16(af, bg[n], acc[m][n], 0, 0, 0); \
            }                                                                  \
        }                                                                      \
    } while (0)

    STAGE(0, 0);
    __syncthreads();
    int cur = 0;
    #pragma unroll 1
    for (int t = 0; t < (DIM / BK) - 1; ++t) {
        STAGE(cur ^ 1, (t + 1) * BK);   // issue next-tile loads FIRST
        COMPUTE(cur);                    // ds_read + MFMA on current
        __syncthreads();                 // one vmcnt(0)+barrier per K-step
        cur ^= 1;
    }
    COMPUTE(cur);

    // ---- fused epilogue ----
    // C/D map: col = lane&15, row = (lane>>4)*4 + r  (m89-verified)
    const int colbase = col0 + wn * 64;
    const int hi = lane >> 4;
    float csq[4]; int clb[4];
    #pragma unroll
    for (int n = 0; n < 4; ++n) {
        int cg = colbase + n * 16 + (lane & 15);
        csq[n] = sq[cg];
        clb[n] = labels[cg];
    }
    float cpos[4] = {0.f, 0.f, 0.f, 0.f};
    float cneg[4] = {0.f, 0.f, 0.f, 0.f};

    // LDS cross-wave reduction scratch (reuses As; all ds_reads done after
    // this barrier)
    __syncthreads();
    float* rp = (float*)As;        // [wn*256 + row_local]  1024 f
    float* rn = rp + 1024;         // 1024 f
    float* cp = rp + 2048;         // [wm*256 + col_local]   512 f
    float* cn = rp + 2560;         //  512 f

    #pragma unroll
    for (int m = 0; m < 8; ++m) {
        #pragma unroll
        for (int r = 0; r < 4; ++r) {
            const int rowl = wm * 128 + m * 16 + hi * 4 + r;
            const int rg = row0 + rowl;
            const float rs = sq[rg];
            const int   rl = labels[rg];
            float pos = 0.f, neg = 0.f;
            #pragma unroll
            for (int n = 0; n < 4; ++n) {
                float d2   = rs + csq[n] - 2.0f * acc[m][n][r];
                float dist = d2 > 0.f ? sqrtf(d2) : 0.f;
                int cg = colbase + n * 16 + (lane & 15);
                if (cg == rg) dist = 0.f;          // exact-zero diagonal
                bool same = (rl == clb[n]);
                float dp = same ? dist : 0.f;
                float dn = same ? 0.f : dist;
                pos += dp;  neg += dn;
                cpos[n] += dp;  cneg[n] += dn;     // column sums (symmetry)
            }
            #pragma unroll
            for (int s = 1; s < 16; s <<= 1) {
                pos += __shfl_xor(pos, s);
                neg += __shfl_xor(neg, s);
            }
            if ((lane & 15) == 0) {
                rp[wn * 256 + rowl] = pos;
                rn[wn * 256 + rowl] = neg;
            }
        }
    }

    #pragma unroll
    for (int n = 0; n < 4; ++n) {
        cpos[n] += __shfl_xor(cpos[n], 16);
        cpos[n] += __shfl_xor(cpos[n], 32);
        cneg[n] += __shfl_xor(cneg[n], 16);
        cneg[n] += __shfl_xor(cneg[n], 32);
        if (lane < 16) {
            int coll = wn * 64 + n * 16 + lane;
            cp[wm * 256 + coll] = cpos[n];
            cn[wm * 256 + coll] = cneg[n];
        }
    }
    __syncthreads();

    // unique-writer plain stores (no atomics, no zero-init needed)
    if (tid < 256) {
        float p  = rp[tid] + rp[256 + tid] + rp[512 + tid] + rp[768 + tid];
        float nn = rn[tid] + rn[256 + tid] + rn[512 + tid] + rn[768 + tid];
        partial_pos[(size_t)tn * NROW + row0 + tid] = p;
        partial_neg[(size_t)tn * NROW + row0 + tid] = nn;
        if (offdiag) {
            float p2 = cp[tid] + cp[256 + tid];
            float n2 = cn[tid] + cn[256 + tid];
            partial_pos[(size_t)tm * NROW + col0 + tid] = p2;
            partial_neg[(size_t)tm * NROW + col0 + tid] = n2;
        }
    }
#undef STAGE
#undef COMPUTE
}

// ---------------------------------------------------------------------------
// row loss: sum the 32 per-slot partials, then margin/relu/reduce.
// ---------------------------------------------------------------------------
__global__ __launch_bounds__(256) void rowloss_kernel(
    const float* __restrict__ partial_pos, const float* __restrict__ partial_neg,
    const int* __restrict__ labels, const int* __restrict__ hist,
    float* __restrict__ totals)
{
    const int i = blockIdx.x * 256 + threadIdx.x;
    float ps = 0.f, ns = 0.f;
    #pragma unroll
    for (int s = 0; s < NT; ++s) {
        ps += partial_pos[(size_t)s * NROW + i];
        ns += partial_neg[(size_t)s * NROW + i];
    }
    const float pc = (float)hist[labels[i]];        // includes self
    const float nc = (float)NROW - pc;
    const float pm = ps / fmaxf(pc, 1.f);
    const float nm = ns / fmaxf(nc, 1.f);
    const bool valid = (pc > 1.f) && (nc > 0.f);
    float t = valid ? fmaxf(pm - nm + 1.0f, 0.f) : 0.f;
    float c = valid ? 1.f : 0.f;
    #pragma unroll
    for (int s = 1; s < 64; s <<= 1) {
        t += __shfl_xor(t, s);
        c += __shfl_xor(c, s);
    }
    if ((threadIdx.x & 63) == 0) {
        atomicAdd(&totals[0], t);
        atomicAdd(&totals[1], c);
    }
}

__global__ void finalize_kernel(const float* __restrict__ totals,
                                float* __restrict__ out)
{
    out[0] = totals[0] / fmaxf(totals[1], 1.f);
}

// ---------------------------------------------------------------------------
extern "C" void kernel_launch(void* const* d_in, const int* in_sizes, int n_in,
                              void* d_out, int out_size, void* d_ws, size_t ws_size,
                              hipStream_t stream) {
    (void)in_sizes; (void)n_in; (void)out_size; (void)ws_size;
    const float* z      = (const float*)d_in[0];
    const int*   labels = (const int*)d_in[1];
    float*       out    = (float*)d_out;

    char* ws = (char*)d_ws;
    float* partial_pos = (float*)(ws);                      // 1 MiB (32 x 8192 f32)
    float* partial_neg = (float*)(ws + 1048576);            // 1 MiB
    int*   hist    = (int*)  (ws + 2097152);                // 256 B
    float* totals  = (float*)(ws + 2097408);                // 8 B
    unsigned short* zbf = (unsigned short*)(ws + 2097664);  // 8 MiB
    float* sq      = (float*)(ws + 2097664 + (size_t)NROW * DIM * 2); // 32 KiB

    // zero only hist+totals (partials are written exactly once per launch)
    hipMemsetAsync(ws + 2097152, 0, 264, stream);

    prep_kernel    <<<NROW / 4, 256, 0, stream>>>(z, labels, zbf, sq, hist);
    tile_kernel    <<<NBLK, 512, 0, stream>>>(zbf, sq, labels, partial_pos, partial_neg);
    rowloss_kernel <<<NROW / 256, 256, 0, stream>>>(partial_pos, partial_neg, labels, hist, totals);
    finalize_kernel<<<1, 1, 0, stream>>>(totals, out);
}